// Round 2
// baseline (1410.605 us; speedup 1.0000x reference)
//
#include <hip/hip_runtime.h>

// Problem: N=50000 nodes, E=800000 edges, D=128.
// Inputs: h[N,128] f32, r[N,1] f32 (UNUSED), src[E] int (32 or 64 — detected),
// dst[E] int. Output: out[N,128] f32.
//
// agg[v] = sum_{e:dst=v} (h[src_e] - h[dst_e])
//        = (sum_{e:dst=v} h[src_e]) - indeg[v]*h[v]
// out[v] = agg[v] / (||agg[v]||_2 + 1e-7)
//
// agg accumulates directly in d_out (f32, same size). d_ws holds indeg + flag.

#define DIM 128

__device__ __forceinline__ int load_idx(const int* __restrict__ p, int e, int is32) {
    // int64 little-endian: value in even word (indices < 2^31)
    return is32 ? p[e] : p[2 * e];
}

// Detect index width: if dst is int64, the odd words of the first 2048 words
// (= high halves of the first 1024 values) are all zero. If int32, they are
// real node indices, almost surely nonzero somewhere. Sets flag=1 for int32.
__global__ void detect_kernel(const int* __restrict__ dst, int* __restrict__ flag) {
    int t = threadIdx.x + blockIdx.x * blockDim.x;  // 1024 threads
    if (dst[2 * t + 1] != 0) atomicOr(flag, 1);
}

__global__ void indeg_kernel(const int* __restrict__ dst,
                             int* __restrict__ indeg,
                             const int* __restrict__ flag, int E) {
    int e = blockIdx.x * blockDim.x + threadIdx.x;
    if (e < E) atomicAdd(&indeg[load_idx(dst, e, *flag)], 1);
}

// 32 threads per edge, each handling 4 floats (one float4 = 16B).
// Scatter h[src] into agg(=out) with f32 atomics.
__global__ void scatter_kernel(const float* __restrict__ h,
                               const int* __restrict__ src,
                               const int* __restrict__ dst,
                               float* __restrict__ agg,
                               const int* __restrict__ flag, int E) {
    int gid = blockIdx.x * blockDim.x + threadIdx.x;
    int e = gid >> 5;
    if (e >= E) return;
    int c = gid & 31;                       // 4 floats per thread
    int is32 = *flag;
    int s = load_idx(src, e, is32);
    int d = load_idx(dst, e, is32);
    float4 v = *reinterpret_cast<const float4*>(h + (size_t)s * DIM + (size_t)c * 4);
    float* ap = agg + (size_t)d * DIM + (size_t)c * 4;
    atomicAdd(ap + 0, v.x);
    atomicAdd(ap + 1, v.y);
    atomicAdd(ap + 2, v.z);
    atomicAdd(ap + 3, v.w);
}

// One wave per node; lane handles 2 consecutive floats. In-place on d_out.
__global__ void finalize_kernel(const float* __restrict__ h,
                                float* __restrict__ out,
                                const int* __restrict__ indeg, int N) {
    int w = blockIdx.x * (blockDim.x >> 6) + (threadIdx.x >> 6);
    int lane = threadIdx.x & 63;
    if (w >= N) return;
    size_t base = (size_t)w * DIM + (size_t)lane * 2;
    float2 a = *reinterpret_cast<const float2*>(out + base);
    float2 hv = *reinterpret_cast<const float2*>(h + base);
    float deg = (float)indeg[w];
    float x0 = a.x - deg * hv.x;
    float x1 = a.y - deg * hv.y;
    float s = x0 * x0 + x1 * x1;
#pragma unroll
    for (int off = 32; off > 0; off >>= 1) s += __shfl_xor(s, off);
    float inv = 1.0f / (sqrtf(s) + 1e-7f);
    float2 o;
    o.x = x0 * inv;
    o.y = x1 * inv;
    *reinterpret_cast<float2*>(out + base) = o;
}

extern "C" void kernel_launch(void* const* d_in, const int* in_sizes, int n_in,
                              void* d_out, int out_size, void* d_ws, size_t ws_size,
                              hipStream_t stream) {
    const float* h  = (const float*)d_in[0];   // f32 [N,128]
    // d_in[1] = r, unused by the reference
    const int* src = (const int*)d_in[2];
    const int* dst = (const int*)d_in[3];
    float* out = (float*)d_out;

    const int N = in_sizes[0] / DIM;   // 50000
    const int E = in_sizes[2];         // 800000

    int* indeg = (int*)d_ws;                       // N ints
    int* flag  = (int*)((char*)d_ws + (size_t)N * sizeof(int));

    // zero agg (accumulated in d_out), indeg, flag
    hipMemsetAsync(d_out, 0, (size_t)out_size * sizeof(float), stream);
    hipMemsetAsync(d_ws, 0, (size_t)N * sizeof(int) + sizeof(int), stream);

    detect_kernel<<<4, 256, 0, stream>>>(dst, flag);

    {
        int threads = 256;
        int blocks = (E + threads - 1) / threads;
        indeg_kernel<<<blocks, threads, 0, stream>>>(dst, indeg, flag, E);
    }
    {
        long long total = (long long)E * 32;
        int threads = 256;
        int blocks = (int)((total + threads - 1) / threads);
        scatter_kernel<<<blocks, threads, 0, stream>>>(h, src, dst, out, flag, E);
    }
    {
        int threads = 256;                       // 4 waves per block
        int blocks = (N + 3) / 4;
        finalize_kernel<<<blocks, threads, 0, stream>>>(h, out, indeg, N);
    }
}

// Round 3
// 206.683 us; speedup vs baseline: 6.8250x; 6.8250x over previous
//
#include <hip/hip_runtime.h>

// Problem: N=50000 nodes, E=800000 edges, D=128.
// Inputs: h[N,128] f32, r[N,1] f32 (UNUSED), src[E] int (32/64 detected),
// dst[E] int. Output: out[N,128] f32.
//
// agg[v] = sum_{e:dst=v} h[src_e] - indeg[v]*h[v]
// out[v] = agg[v] / (||agg[v]||_2 + 1e-7)
//
// Strategy: CSR-group edges by dst (histogram + scan + bucket), then one
// wave per node gathers h[src] rows and accumulates in registers — no f32
// atomics at all.

#define DIM 128

__device__ __forceinline__ int load_idx(const int* __restrict__ p, int e, int is32) {
    return is32 ? p[e] : p[2 * e];   // int64 LE: value in even word
}

// Detect index width (int32 vs int64) from high words of first 1024 values.
__global__ void detect_kernel(const int* __restrict__ dst, int* __restrict__ flag) {
    int t = threadIdx.x + blockIdx.x * blockDim.x;  // 1024 threads
    if (dst[2 * t + 1] != 0) atomicOr(flag, 1);
}

__global__ void indeg_kernel(const int* __restrict__ dst,
                             int* __restrict__ indeg,
                             const int* __restrict__ flag, int E) {
    int e = blockIdx.x * blockDim.x + threadIdx.x;
    if (e < E) atomicAdd(&indeg[load_idx(dst, e, *flag)], 1);
}

// Single-block exclusive scan of indeg -> offsets[N+1] and cursor[N].
// 1024 threads: per-wave shfl scan + tiny LDS cross-wave scan.
__global__ void scan_kernel(const int* __restrict__ indeg,
                            int* __restrict__ offsets,
                            int* __restrict__ cursor, int N) {
    __shared__ int wsum[16];
    __shared__ int wbase[16];
    __shared__ int carry_s;
    if (threadIdx.x == 0) carry_s = 0;
    __syncthreads();
    int lane = threadIdx.x & 63, wid = threadIdx.x >> 6;
    for (int base = 0; base < N; base += 1024) {
        int i = base + threadIdx.x;
        int v = (i < N) ? indeg[i] : 0;
        int x = v;
#pragma unroll
        for (int off = 1; off < 64; off <<= 1) {
            int t = __shfl_up(x, off);
            if (lane >= off) x += t;
        }
        if (lane == 63) wsum[wid] = x;
        __syncthreads();
        if (threadIdx.x == 0) {
            int run = carry_s;
#pragma unroll
            for (int w = 0; w < 16; ++w) { wbase[w] = run; run += wsum[w]; }
            carry_s = run;
        }
        __syncthreads();
        int excl = x - v + wbase[wid];
        if (i < N) { offsets[i] = excl; cursor[i] = excl; }
        __syncthreads();   // protect wsum/carry before next chunk
    }
    if (threadIdx.x == 0) offsets[N] = carry_s;
}

// Scatter src indices into CSR buckets (int atomics on cursors only).
__global__ void bucket_kernel(const int* __restrict__ src,
                              const int* __restrict__ dst,
                              int* __restrict__ cursor,
                              int* __restrict__ esrc,
                              const int* __restrict__ flag, int E) {
    int e = blockIdx.x * blockDim.x + threadIdx.x;
    if (e >= E) return;
    int is32 = *flag;
    int s = load_idx(src, e, is32);
    int d = load_idx(dst, e, is32);
    int pos = atomicAdd(&cursor[d], 1);
    esrc[pos] = s;
}

// One wave per node: gather h[src] rows, accumulate in regs, subtract
// deg*h[v], L2-normalize, write. Lane owns columns [2*lane, 2*lane+1].
__global__ void gather_kernel(const float* __restrict__ h,
                              const int* __restrict__ offsets,
                              const int* __restrict__ esrc,
                              float* __restrict__ out, int N) {
    int v = blockIdx.x * (blockDim.x >> 6) + (threadIdx.x >> 6);
    int lane = threadIdx.x & 63;
    if (v >= N) return;
    int start = offsets[v], end = offsets[v + 1];
    float deg = (float)(end - start);
    size_t col = (size_t)lane * 2;
    float2 hv = *reinterpret_cast<const float2*>(h + (size_t)v * DIM + col);

    float a0x = 0.f, a0y = 0.f, a1x = 0.f, a1y = 0.f;
    float a2x = 0.f, a2y = 0.f, a3x = 0.f, a3y = 0.f;
    int e = start;
    for (; e + 4 <= end; e += 4) {
        int s0 = esrc[e], s1 = esrc[e + 1], s2 = esrc[e + 2], s3 = esrc[e + 3];
        float2 v0 = *reinterpret_cast<const float2*>(h + (size_t)s0 * DIM + col);
        float2 v1 = *reinterpret_cast<const float2*>(h + (size_t)s1 * DIM + col);
        float2 v2 = *reinterpret_cast<const float2*>(h + (size_t)s2 * DIM + col);
        float2 v3 = *reinterpret_cast<const float2*>(h + (size_t)s3 * DIM + col);
        a0x += v0.x; a0y += v0.y;
        a1x += v1.x; a1y += v1.y;
        a2x += v2.x; a2y += v2.y;
        a3x += v3.x; a3y += v3.y;
    }
    for (; e < end; ++e) {
        int s0 = esrc[e];
        float2 v0 = *reinterpret_cast<const float2*>(h + (size_t)s0 * DIM + col);
        a0x += v0.x; a0y += v0.y;
    }
    float x0 = (a0x + a1x) + (a2x + a3x) - deg * hv.x;
    float x1 = (a0y + a1y) + (a2y + a3y) - deg * hv.y;

    float s = x0 * x0 + x1 * x1;
#pragma unroll
    for (int off = 32; off > 0; off >>= 1) s += __shfl_xor(s, off);
    float inv = 1.0f / (sqrtf(s) + 1e-7f);
    float2 o;
    o.x = x0 * inv;
    o.y = x1 * inv;
    *reinterpret_cast<float2*>(out + (size_t)v * DIM + col) = o;
}

extern "C" void kernel_launch(void* const* d_in, const int* in_sizes, int n_in,
                              void* d_out, int out_size, void* d_ws, size_t ws_size,
                              hipStream_t stream) {
    const float* h = (const float*)d_in[0];   // f32 [N,128]
    // d_in[1] = r, unused
    const int* src = (const int*)d_in[2];
    const int* dst = (const int*)d_in[3];
    float* out = (float*)d_out;

    const int N = in_sizes[0] / DIM;   // 50000
    const int E = in_sizes[2];         // 800000

    // Workspace layout (ints): indeg[N], offsets[N+1], cursor[N], esrc[E], flag[1]
    int* indeg   = (int*)d_ws;
    int* offsets = indeg + N;
    int* cursor  = offsets + N + 1;
    int* esrc    = cursor + N;
    int* flag    = esrc + E;

    // zero indeg + flag (offsets/cursor/esrc fully overwritten)
    hipMemsetAsync(indeg, 0, (size_t)N * sizeof(int), stream);
    hipMemsetAsync(flag, 0, sizeof(int), stream);

    detect_kernel<<<4, 256, 0, stream>>>(dst, flag);

    {
        int threads = 256;
        int blocks = (E + threads - 1) / threads;
        indeg_kernel<<<blocks, threads, 0, stream>>>(dst, indeg, flag, E);
    }
    scan_kernel<<<1, 1024, 0, stream>>>(indeg, offsets, cursor, N);
    {
        int threads = 256;
        int blocks = (E + threads - 1) / threads;
        bucket_kernel<<<blocks, threads, 0, stream>>>(src, dst, cursor, esrc, flag, E);
    }
    {
        int threads = 256;   // 4 waves per block
        int blocks = (N + 3) / 4;
        gather_kernel<<<blocks, threads, 0, stream>>>(h, offsets, esrc, out, N);
    }
}

// Round 4
// 204.533 us; speedup vs baseline: 6.8967x; 1.0105x over previous
//
#include <hip/hip_runtime.h>

// Problem: N=50000 nodes, E=800000 edges, D=128.
// Inputs: h[N,128] f32, r[N,1] f32 (UNUSED), src[E] int (32/64 detected),
// dst[E] int. Output: out[N,128] f32.
//
// agg[v] = sum_{e:dst=v} h[src_e] - indeg[v]*h[v]
// out[v] = agg[v] / (||agg[v]||_2 + 1e-7)
//
// Round-4 strategy: XCD-private chunked CSR. Edges split into 8 contiguous
// chunks; each chunk has private histogram/scan/cursor and a private esrc
// segment. chunk = blockIdx%8 maps each chunk's blocks to one XCD (round-
// robin dispatch), so scatter writes stay resident in that XCD's L2 —
// kills the 52 MB partial-line writeback seen in round 3.

#define DIM 128
#define NCHUNK 8

__device__ __forceinline__ int load_idx(const int* __restrict__ p, int e, int is32) {
    return is32 ? p[e] : p[2 * e];   // int64 LE: value in even word
}

// Detect index width (int32 vs int64) from high words of first 1024 values.
__global__ void detect_kernel(const int* __restrict__ dst, int* __restrict__ flag) {
    int t = threadIdx.x + blockIdx.x * blockDim.x;  // 1024 threads
    if (dst[2 * t + 1] != 0) atomicOr(flag, 1);
}

// Per-chunk histogram of dst. chunk = blockIdx%8 (XCD-local counters).
__global__ void hist8_kernel(const int* __restrict__ dst,
                             int* __restrict__ cnt8,      // [NCHUNK][N]
                             const int* __restrict__ flag,
                             int E, int chunkSize, int N) {
    int c = blockIdx.x & (NCHUNK - 1);
    int i = (blockIdx.x >> 3) * blockDim.x + threadIdx.x;
    int e = c * chunkSize + i;
    if (i >= chunkSize || e >= E) return;
    int d = load_idx(dst, e, *flag);
    atomicAdd(&cnt8[c * N + d], 1);
}

// 8 blocks: block c scans chunk c's histogram -> offsets8[c][0..N] (+cursor).
__global__ void scan8_kernel(const int* __restrict__ cnt8,
                             int* __restrict__ offsets8,   // [NCHUNK][N+1]
                             int* __restrict__ cursor8,    // [NCHUNK][N]
                             int N) {
    __shared__ int wsum[16];
    __shared__ int wbase[16];
    __shared__ int carry_s;
    int c = blockIdx.x;
    const int* cnt = cnt8 + c * N;
    int* offsets = offsets8 + c * (N + 1);
    int* cursor = cursor8 + c * N;
    if (threadIdx.x == 0) carry_s = 0;
    __syncthreads();
    int lane = threadIdx.x & 63, wid = threadIdx.x >> 6;
    for (int base = 0; base < N; base += 1024) {
        int i = base + threadIdx.x;
        int v = (i < N) ? cnt[i] : 0;
        int x = v;
#pragma unroll
        for (int off = 1; off < 64; off <<= 1) {
            int t = __shfl_up(x, off);
            if (lane >= off) x += t;
        }
        if (lane == 63) wsum[wid] = x;
        __syncthreads();
        if (threadIdx.x == 0) {
            int run = carry_s;
#pragma unroll
            for (int w = 0; w < 16; ++w) { wbase[w] = run; run += wsum[w]; }
            carry_s = run;
        }
        __syncthreads();
        int excl = x - v + wbase[wid];
        if (i < N) { offsets[i] = excl; cursor[i] = excl; }
        __syncthreads();
    }
    if (threadIdx.x == 0) offsets[N] = carry_s;
}

// Per-chunk bucket: scatter src indices into chunk-private esrc segment.
__global__ void bucket8_kernel(const int* __restrict__ src,
                               const int* __restrict__ dst,
                               int* __restrict__ cursor8,   // [NCHUNK][N]
                               int* __restrict__ esrc,      // [E] chunk-major
                               const int* __restrict__ flag,
                               int E, int chunkSize, int N) {
    int c = blockIdx.x & (NCHUNK - 1);
    int i = (blockIdx.x >> 3) * blockDim.x + threadIdx.x;
    int e = c * chunkSize + i;
    if (i >= chunkSize || e >= E) return;
    int is32 = *flag;
    int s = load_idx(src, e, is32);
    int d = load_idx(dst, e, is32);
    int pos = atomicAdd(&cursor8[c * N + d], 1);
    esrc[c * chunkSize + pos] = s;
}

// One wave per node: walk the 8 chunk segments, accumulate h[src] rows in
// regs, subtract deg*h[v], L2-normalize, write. Lane owns 2 columns.
__global__ void gather_kernel(const float* __restrict__ h,
                              const int* __restrict__ offsets8,  // [NCHUNK][N+1]
                              const int* __restrict__ esrc,
                              float* __restrict__ out,
                              int N, int chunkSize) {
    int v = blockIdx.x * (blockDim.x >> 6) + (threadIdx.x >> 6);
    int lane = threadIdx.x & 63;
    if (v >= N) return;
    size_t col = (size_t)lane * 2;
    float2 hv = *reinterpret_cast<const float2*>(h + (size_t)v * DIM + col);

    float a0x = 0.f, a0y = 0.f, a1x = 0.f, a1y = 0.f;
    int deg = 0;
#pragma unroll
    for (int c = 0; c < NCHUNK; ++c) {
        int st = offsets8[c * (N + 1) + v];
        int en = offsets8[c * (N + 1) + v + 1];
        deg += en - st;
        const int* ep = esrc + c * chunkSize;
        int e = st;
        for (; e + 2 <= en; e += 2) {
            int s0 = ep[e], s1 = ep[e + 1];
            float2 v0 = *reinterpret_cast<const float2*>(h + (size_t)s0 * DIM + col);
            float2 v1 = *reinterpret_cast<const float2*>(h + (size_t)s1 * DIM + col);
            a0x += v0.x; a0y += v0.y;
            a1x += v1.x; a1y += v1.y;
        }
        if (e < en) {
            int s0 = ep[e];
            float2 v0 = *reinterpret_cast<const float2*>(h + (size_t)s0 * DIM + col);
            a0x += v0.x; a0y += v0.y;
        }
    }
    float degf = (float)deg;
    float x0 = (a0x + a1x) - degf * hv.x;
    float x1 = (a0y + a1y) - degf * hv.y;

    float s = x0 * x0 + x1 * x1;
#pragma unroll
    for (int off = 32; off > 0; off >>= 1) s += __shfl_xor(s, off);
    float inv = 1.0f / (sqrtf(s) + 1e-7f);
    float2 o;
    o.x = x0 * inv;
    o.y = x1 * inv;
    *reinterpret_cast<float2*>(out + (size_t)v * DIM + col) = o;
}

extern "C" void kernel_launch(void* const* d_in, const int* in_sizes, int n_in,
                              void* d_out, int out_size, void* d_ws, size_t ws_size,
                              hipStream_t stream) {
    const float* h = (const float*)d_in[0];   // f32 [N,128]
    // d_in[1] = r, unused
    const int* src = (const int*)d_in[2];
    const int* dst = (const int*)d_in[3];
    float* out = (float*)d_out;

    const int N = in_sizes[0] / DIM;   // 50000
    const int E = in_sizes[2];         // 800000
    const int chunkSize = (E + NCHUNK - 1) / NCHUNK;   // 100000

    // Workspace (ints): cnt8[8N], offsets8[8(N+1)], cursor8[8N], esrc[E], flag
    int* cnt8     = (int*)d_ws;
    int* offsets8 = cnt8 + NCHUNK * N;
    int* cursor8  = offsets8 + NCHUNK * (N + 1);
    int* esrc     = cursor8 + NCHUNK * N;
    int* flag     = esrc + E;

    hipMemsetAsync(cnt8, 0, (size_t)NCHUNK * N * sizeof(int), stream);
    hipMemsetAsync(flag, 0, sizeof(int), stream);

    detect_kernel<<<4, 256, 0, stream>>>(dst, flag);

    {
        int threads = 256;
        int blocksPerChunk = (chunkSize + threads - 1) / threads;
        hist8_kernel<<<NCHUNK * blocksPerChunk, threads, 0, stream>>>(
            dst, cnt8, flag, E, chunkSize, N);
    }
    scan8_kernel<<<NCHUNK, 1024, 0, stream>>>(cnt8, offsets8, cursor8, N);
    {
        int threads = 256;
        int blocksPerChunk = (chunkSize + threads - 1) / threads;
        bucket8_kernel<<<NCHUNK * blocksPerChunk, threads, 0, stream>>>(
            src, dst, cursor8, esrc, flag, E, chunkSize, N);
    }
    {
        int threads = 256;   // 4 waves per block
        int blocks = (N + 3) / 4;
        gather_kernel<<<blocks, threads, 0, stream>>>(h, offsets8, esrc, out, N, chunkSize);
    }
}

// Round 5
// 157.649 us; speedup vs baseline: 8.9478x; 1.2974x over previous
//
#include <hip/hip_runtime.h>

// Problem: N=50000 nodes, E=800000 edges, D=128.
// Inputs: h[N,128] f32, r[N,1] f32 (UNUSED), src[E] int (32/64 detected),
// dst[E] int. Output: out[N,128] f32.
//
// agg[v] = sum_{e:dst=v} h[src_e] - indeg[v]*h[v]
// out[v] = agg[v] / (||agg[v]||_2 + 1e-7)
//
// Round-5: XCD-private histograms + cursors (fast atomics), but bucket
// writes into a GLOBALLY CONTIGUOUS per-node CSR segment so the gather
// walks one segment per node with an 8-way unrolled, high-MLP loop.

#define DIM 128
#define NCHUNK 8

__device__ __forceinline__ int load_idx(const int* __restrict__ p, int e, int is32) {
    return is32 ? p[e] : p[2 * e];   // int64 LE: value in even word
}

// Detect index width (int32 vs int64) from high words of first 1024 values.
__global__ void detect_kernel(const int* __restrict__ dst, int* __restrict__ flag) {
    int t = threadIdx.x + blockIdx.x * blockDim.x;  // 1024 threads
    if (dst[2 * t + 1] != 0) atomicOr(flag, 1);
}

// Per-chunk histogram of dst. chunk = blockIdx%8 -> XCD-local counters.
__global__ void hist8_kernel(const int* __restrict__ dst,
                             int* __restrict__ cnt8,      // [NCHUNK][N]
                             const int* __restrict__ flag,
                             int E, int chunkSize, int N) {
    int c = blockIdx.x & (NCHUNK - 1);
    int i = (blockIdx.x >> 3) * blockDim.x + threadIdx.x;
    int e = c * chunkSize + i;
    if (i >= chunkSize || e >= E) return;
    int d = load_idx(dst, e, *flag);
    atomicAdd(&cnt8[c * N + d], 1);
}

// S1: per-block sums of total degree (deg[v] = sum_c cnt8[c][v]).
__global__ void degsum_kernel(const int* __restrict__ cnt8,
                              int* __restrict__ bsum, int N) {
    int v = blockIdx.x * blockDim.x + threadIdx.x;
    int deg = 0;
    if (v < N) {
#pragma unroll
        for (int c = 0; c < NCHUNK; ++c) deg += cnt8[c * N + v];
    }
    __shared__ int ws_[4];
    int lane = threadIdx.x & 63, wid = threadIdx.x >> 6;
    int x = deg;
#pragma unroll
    for (int off = 32; off > 0; off >>= 1) x += __shfl_xor(x, off);
    if (lane == 0) ws_[wid] = x;
    __syncthreads();
    if (threadIdx.x == 0) bsum[blockIdx.x] = ws_[0] + ws_[1] + ws_[2] + ws_[3];
}

// S2: single block scans bsum[NB] -> boff (exclusive); writes goff[N]=total.
// NB <= 256.
__global__ void bscan_kernel(const int* __restrict__ bsum,
                             int* __restrict__ boff,
                             int* __restrict__ goff, int NB, int N) {
    __shared__ int wsum[4];
    __shared__ int wbase[4];
    int t = threadIdx.x;
    int lane = t & 63, wid = t >> 6;
    int v = (t < NB) ? bsum[t] : 0;
    int x = v;
#pragma unroll
    for (int off = 1; off < 64; off <<= 1) {
        int y = __shfl_up(x, off);
        if (lane >= off) x += y;
    }
    if (lane == 63) wsum[wid] = x;
    __syncthreads();
    if (t == 0) {
        int run = 0;
#pragma unroll
        for (int w = 0; w < 4; ++w) { wbase[w] = run; run += wsum[w]; }
    }
    __syncthreads();
    int incl = x + wbase[wid];
    if (t < NB) boff[t] = incl - v;
    if (t == 255) goff[N] = wbase[3] + wsum[3];
}

// S3: per node: goff[v] = boff[block] + block-local exclusive scan of deg;
// cursor8[c][v] = goff[v] + sum_{c'<c} cnt8[c'][v].
__global__ void offsets_kernel(const int* __restrict__ cnt8,
                               const int* __restrict__ boff,
                               int* __restrict__ goff,
                               int* __restrict__ cursor8, int N) {
    __shared__ int wsum[4];
    __shared__ int wbase[4];
    int v = blockIdx.x * blockDim.x + threadIdx.x;
    int lane = threadIdx.x & 63, wid = threadIdx.x >> 6;
    int cv[NCHUNK];
    int deg = 0;
    if (v < N) {
#pragma unroll
        for (int c = 0; c < NCHUNK; ++c) { cv[c] = cnt8[c * N + v]; deg += cv[c]; }
    }
    int x = deg;
#pragma unroll
    for (int off = 1; off < 64; off <<= 1) {
        int y = __shfl_up(x, off);
        if (lane >= off) x += y;
    }
    if (lane == 63) wsum[wid] = x;
    __syncthreads();
    if (threadIdx.x == 0) {
        int run = 0;
#pragma unroll
        for (int w = 0; w < 4; ++w) { wbase[w] = run; run += wsum[w]; }
    }
    __syncthreads();
    if (v < N) {
        int excl = x - deg + wbase[wid] + boff[blockIdx.x];
        goff[v] = excl;
        int run = excl;
#pragma unroll
        for (int c = 0; c < NCHUNK; ++c) { cursor8[c * N + v] = run; run += cv[c]; }
    }
}

// Bucket: chunk-private cursor atomics, writes into global per-node segment.
__global__ void bucket8_kernel(const int* __restrict__ src,
                               const int* __restrict__ dst,
                               int* __restrict__ cursor8,   // [NCHUNK][N]
                               int* __restrict__ esrc,      // [E] global CSR
                               const int* __restrict__ flag,
                               int E, int chunkSize, int N) {
    int c = blockIdx.x & (NCHUNK - 1);
    int i = (blockIdx.x >> 3) * blockDim.x + threadIdx.x;
    int e = c * chunkSize + i;
    if (i >= chunkSize || e >= E) return;
    int is32 = *flag;
    int s = load_idx(src, e, is32);
    int d = load_idx(dst, e, is32);
    int pos = atomicAdd(&cursor8[c * N + d], 1);
    esrc[pos] = s;
}

// One wave per node: 8-way unrolled gather of h[src] rows, subtract
// deg*h[v], L2-normalize, write. Lane owns columns [2*lane, 2*lane+1].
__global__ void gather_kernel(const float* __restrict__ h,
                              const int* __restrict__ goff,
                              const int* __restrict__ esrc,
                              float* __restrict__ out, int N) {
    int v = blockIdx.x * (blockDim.x >> 6) + (threadIdx.x >> 6);
    int lane = threadIdx.x & 63;
    if (v >= N) return;
    int start = goff[v], end = goff[v + 1];
    float degf = (float)(end - start);
    size_t col = (size_t)lane * 2;
    float2 hv = *reinterpret_cast<const float2*>(h + (size_t)v * DIM + col);

    float a0x = 0.f, a0y = 0.f, a1x = 0.f, a1y = 0.f;
    float a2x = 0.f, a2y = 0.f, a3x = 0.f, a3y = 0.f;
    int e = start;
    for (; e + 8 <= end; e += 8) {
        int s0 = esrc[e],     s1 = esrc[e + 1], s2 = esrc[e + 2], s3 = esrc[e + 3];
        int s4 = esrc[e + 4], s5 = esrc[e + 5], s6 = esrc[e + 6], s7 = esrc[e + 7];
        float2 v0 = *reinterpret_cast<const float2*>(h + (size_t)s0 * DIM + col);
        float2 v1 = *reinterpret_cast<const float2*>(h + (size_t)s1 * DIM + col);
        float2 v2 = *reinterpret_cast<const float2*>(h + (size_t)s2 * DIM + col);
        float2 v3 = *reinterpret_cast<const float2*>(h + (size_t)s3 * DIM + col);
        float2 v4 = *reinterpret_cast<const float2*>(h + (size_t)s4 * DIM + col);
        float2 v5 = *reinterpret_cast<const float2*>(h + (size_t)s5 * DIM + col);
        float2 v6 = *reinterpret_cast<const float2*>(h + (size_t)s6 * DIM + col);
        float2 v7 = *reinterpret_cast<const float2*>(h + (size_t)s7 * DIM + col);
        a0x += v0.x; a0y += v0.y;  a1x += v1.x; a1y += v1.y;
        a2x += v2.x; a2y += v2.y;  a3x += v3.x; a3y += v3.y;
        a0x += v4.x; a0y += v4.y;  a1x += v5.x; a1y += v5.y;
        a2x += v6.x; a2y += v6.y;  a3x += v7.x; a3y += v7.y;
    }
    if (e + 4 <= end) {
        int s0 = esrc[e], s1 = esrc[e + 1], s2 = esrc[e + 2], s3 = esrc[e + 3];
        float2 v0 = *reinterpret_cast<const float2*>(h + (size_t)s0 * DIM + col);
        float2 v1 = *reinterpret_cast<const float2*>(h + (size_t)s1 * DIM + col);
        float2 v2 = *reinterpret_cast<const float2*>(h + (size_t)s2 * DIM + col);
        float2 v3 = *reinterpret_cast<const float2*>(h + (size_t)s3 * DIM + col);
        a0x += v0.x; a0y += v0.y;  a1x += v1.x; a1y += v1.y;
        a2x += v2.x; a2y += v2.y;  a3x += v3.x; a3y += v3.y;
        e += 4;
    }
    if (e + 2 <= end) {
        int s0 = esrc[e], s1 = esrc[e + 1];
        float2 v0 = *reinterpret_cast<const float2*>(h + (size_t)s0 * DIM + col);
        float2 v1 = *reinterpret_cast<const float2*>(h + (size_t)s1 * DIM + col);
        a0x += v0.x; a0y += v0.y;  a1x += v1.x; a1y += v1.y;
        e += 2;
    }
    if (e < end) {
        int s0 = esrc[e];
        float2 v0 = *reinterpret_cast<const float2*>(h + (size_t)s0 * DIM + col);
        a0x += v0.x; a0y += v0.y;
    }
    float x0 = (a0x + a1x) + (a2x + a3x) - degf * hv.x;
    float x1 = (a0y + a1y) + (a2y + a3y) - degf * hv.y;

    float s = x0 * x0 + x1 * x1;
#pragma unroll
    for (int off = 32; off > 0; off >>= 1) s += __shfl_xor(s, off);
    float inv = 1.0f / (sqrtf(s) + 1e-7f);
    float2 o;
    o.x = x0 * inv;
    o.y = x1 * inv;
    *reinterpret_cast<float2*>(out + (size_t)v * DIM + col) = o;
}

extern "C" void kernel_launch(void* const* d_in, const int* in_sizes, int n_in,
                              void* d_out, int out_size, void* d_ws, size_t ws_size,
                              hipStream_t stream) {
    const float* h = (const float*)d_in[0];   // f32 [N,128]
    // d_in[1] = r, unused
    const int* src = (const int*)d_in[2];
    const int* dst = (const int*)d_in[3];
    float* out = (float*)d_out;

    const int N = in_sizes[0] / DIM;   // 50000
    const int E = in_sizes[2];         // 800000
    const int chunkSize = (E + NCHUNK - 1) / NCHUNK;   // 100000
    const int threads = 256;
    const int NB = (N + threads - 1) / threads;        // 196 (<=256)

    // Workspace (ints): cnt8[8N], cursor8[8N], goff[N+1], bsum[256],
    // boff[256], esrc[E], flag[1]
    int* cnt8    = (int*)d_ws;
    int* cursor8 = cnt8 + NCHUNK * N;
    int* goff    = cursor8 + NCHUNK * N;
    int* bsum    = goff + N + 1;
    int* boff    = bsum + 256;
    int* esrc    = boff + 256;
    int* flag    = esrc + E;

    hipMemsetAsync(cnt8, 0, (size_t)NCHUNK * N * sizeof(int), stream);
    hipMemsetAsync(flag, 0, sizeof(int), stream);

    detect_kernel<<<4, 256, 0, stream>>>(dst, flag);

    {
        int blocksPerChunk = (chunkSize + threads - 1) / threads;
        hist8_kernel<<<NCHUNK * blocksPerChunk, threads, 0, stream>>>(
            dst, cnt8, flag, E, chunkSize, N);
    }
    degsum_kernel<<<NB, threads, 0, stream>>>(cnt8, bsum, N);
    bscan_kernel<<<1, 256, 0, stream>>>(bsum, boff, goff, NB, N);
    offsets_kernel<<<NB, threads, 0, stream>>>(cnt8, boff, goff, cursor8, N);
    {
        int blocksPerChunk = (chunkSize + threads - 1) / threads;
        bucket8_kernel<<<NCHUNK * blocksPerChunk, threads, 0, stream>>>(
            src, dst, cursor8, esrc, flag, E, chunkSize, N);
    }
    {
        int blocks = (N + 3) / 4;   // 4 waves per block
        gather_kernel<<<blocks, threads, 0, stream>>>(h, goff, esrc, out, N);
    }
}

// Round 6
// 137.965 us; speedup vs baseline: 10.2243x; 1.1427x over previous
//
#include <hip/hip_runtime.h>

// Problem: N=50000 nodes, E=800000 edges, D=128.
// Inputs: h[N,128] f32, r[N,1] f32 (UNUSED), src[E] int (32/64 detected),
// dst[E] int. Output: out[N,128] f32.
//
// agg[v] = sum_{e:dst=v} h[src_e] - indeg[v]*h[v]
// out[v] = agg[v] / (||agg[v]||_2 + 1e-7)
//
// Round-6: round-5 structure (XCD-private hist/cursors, contiguous global
// CSR, 8-way unrolled gather) plus:
//   - esrc stored as uint16 (src < 2^16): halves scatter + index traffic
//   - gather reads a bf16 copy of h (halves random-row fetch; f32 accum;
//     exact f32 self-term). Falls back to f32 gather if ws too small.
//   - hist/bucket process 2 edges per thread.

#define DIM 128
#define NCHUNK 8

__device__ __forceinline__ int load_idx(const int* __restrict__ p, int e, int is32) {
    return is32 ? p[e] : p[2 * e];   // int64 LE: value in even word
}

__device__ __forceinline__ unsigned short f32_to_bf16(float f) {
    unsigned int x = __float_as_uint(f);
    unsigned int r = (x + 0x7fffu + ((x >> 16) & 1u)) >> 16;
    return (unsigned short)r;
}

// Detect index width (int32 vs int64) from high words of first 1024 values.
__global__ void detect_kernel(const int* __restrict__ dst, int* __restrict__ flag) {
    int t = threadIdx.x + blockIdx.x * blockDim.x;  // 1024 threads
    if (dst[2 * t + 1] != 0) atomicOr(flag, 1);
}

// Cast h (f32) -> hb (bf16). 4 elements per thread.
__global__ void cast_kernel(const float* __restrict__ h,
                            unsigned short* __restrict__ hb, int total4) {
    int i = blockIdx.x * blockDim.x + threadIdx.x;
    if (i >= total4) return;
    float4 v = *reinterpret_cast<const float4*>(h + (size_t)i * 4);
    ushort4 o;
    o.x = f32_to_bf16(v.x); o.y = f32_to_bf16(v.y);
    o.z = f32_to_bf16(v.z); o.w = f32_to_bf16(v.w);
    *reinterpret_cast<ushort4*>(hb + (size_t)i * 4) = o;
}

// Per-chunk histogram of dst, 2 edges/thread. chunk = blockIdx%8 -> XCD-local.
__global__ void hist8_kernel(const int* __restrict__ dst,
                             int* __restrict__ cnt8,      // [NCHUNK][N]
                             const int* __restrict__ flag,
                             int E, int chunkSize, int N) {
    int c = blockIdx.x & (NCHUNK - 1);
    int i = ((blockIdx.x >> 3) * blockDim.x + threadIdx.x) * 2;
    int is32 = *flag;
    int base = c * chunkSize;
#pragma unroll
    for (int k = 0; k < 2; ++k) {
        int idx = i + k;
        if (idx < chunkSize && base + idx < E) {
            int d = load_idx(dst, base + idx, is32);
            atomicAdd(&cnt8[c * N + d], 1);
        }
    }
}

// S1: per-block sums of total degree.
__global__ void degsum_kernel(const int* __restrict__ cnt8,
                              int* __restrict__ bsum, int N) {
    int v = blockIdx.x * blockDim.x + threadIdx.x;
    int deg = 0;
    if (v < N) {
#pragma unroll
        for (int c = 0; c < NCHUNK; ++c) deg += cnt8[c * N + v];
    }
    __shared__ int ws_[4];
    int lane = threadIdx.x & 63, wid = threadIdx.x >> 6;
    int x = deg;
#pragma unroll
    for (int off = 32; off > 0; off >>= 1) x += __shfl_xor(x, off);
    if (lane == 0) ws_[wid] = x;
    __syncthreads();
    if (threadIdx.x == 0) bsum[blockIdx.x] = ws_[0] + ws_[1] + ws_[2] + ws_[3];
}

// S2: single block scans bsum[NB] -> boff (exclusive); goff[N] = total.
__global__ void bscan_kernel(const int* __restrict__ bsum,
                             int* __restrict__ boff,
                             int* __restrict__ goff, int NB, int N) {
    __shared__ int wsum[4];
    __shared__ int wbase[4];
    int t = threadIdx.x;
    int lane = t & 63, wid = t >> 6;
    int v = (t < NB) ? bsum[t] : 0;
    int x = v;
#pragma unroll
    for (int off = 1; off < 64; off <<= 1) {
        int y = __shfl_up(x, off);
        if (lane >= off) x += y;
    }
    if (lane == 63) wsum[wid] = x;
    __syncthreads();
    if (t == 0) {
        int run = 0;
#pragma unroll
        for (int w = 0; w < 4; ++w) { wbase[w] = run; run += wsum[w]; }
    }
    __syncthreads();
    int incl = x + wbase[wid];
    if (t < NB) boff[t] = incl - v;
    if (t == 255) goff[N] = wbase[3] + wsum[3];
}

// S3: goff[v] + per-chunk cursor bases.
__global__ void offsets_kernel(const int* __restrict__ cnt8,
                               const int* __restrict__ boff,
                               int* __restrict__ goff,
                               int* __restrict__ cursor8, int N) {
    __shared__ int wsum[4];
    __shared__ int wbase[4];
    int v = blockIdx.x * blockDim.x + threadIdx.x;
    int lane = threadIdx.x & 63, wid = threadIdx.x >> 6;
    int cv[NCHUNK];
    int deg = 0;
    if (v < N) {
#pragma unroll
        for (int c = 0; c < NCHUNK; ++c) { cv[c] = cnt8[c * N + v]; deg += cv[c]; }
    }
    int x = deg;
#pragma unroll
    for (int off = 1; off < 64; off <<= 1) {
        int y = __shfl_up(x, off);
        if (lane >= off) x += y;
    }
    if (lane == 63) wsum[wid] = x;
    __syncthreads();
    if (threadIdx.x == 0) {
        int run = 0;
#pragma unroll
        for (int w = 0; w < 4; ++w) { wbase[w] = run; run += wsum[w]; }
    }
    __syncthreads();
    if (v < N) {
        int excl = x - deg + wbase[wid] + boff[blockIdx.x];
        goff[v] = excl;
        int run = excl;
#pragma unroll
        for (int c = 0; c < NCHUNK; ++c) { cursor8[c * N + v] = run; run += cv[c]; }
    }
}

// Bucket: chunk-private cursor atomics, u16 writes into global CSR, 2 edges/thread.
__global__ void bucket8_kernel(const int* __restrict__ src,
                               const int* __restrict__ dst,
                               int* __restrict__ cursor8,        // [NCHUNK][N]
                               unsigned short* __restrict__ esrc,// [E] u16
                               const int* __restrict__ flag,
                               int E, int chunkSize, int N) {
    int c = blockIdx.x & (NCHUNK - 1);
    int i = ((blockIdx.x >> 3) * blockDim.x + threadIdx.x) * 2;
    int is32 = *flag;
    int base = c * chunkSize;
#pragma unroll
    for (int k = 0; k < 2; ++k) {
        int idx = i + k;
        if (idx < chunkSize && base + idx < E) {
            int e = base + idx;
            int s = load_idx(src, e, is32);
            int d = load_idx(dst, e, is32);
            int pos = atomicAdd(&cursor8[c * N + d], 1);
            esrc[pos] = (unsigned short)s;
        }
    }
}

// One wave per node, 8-way unrolled gather. BF16: rows from bf16 copy hb.
template <bool BF16>
__global__ void gather_kernel(const float* __restrict__ h,
                              const unsigned short* __restrict__ hb,
                              const int* __restrict__ goff,
                              const unsigned short* __restrict__ esrc,
                              float* __restrict__ out, int N) {
    int v = blockIdx.x * (blockDim.x >> 6) + (threadIdx.x >> 6);
    int lane = threadIdx.x & 63;
    if (v >= N) return;
    int start = goff[v], end = goff[v + 1];
    float degf = (float)(end - start);
    size_t col = (size_t)lane * 2;
    float2 hv = *reinterpret_cast<const float2*>(h + (size_t)v * DIM + col);

    auto rowld = [&](int s) -> float2 {
        if constexpr (BF16) {
            unsigned int u = *reinterpret_cast<const unsigned int*>(
                hb + (size_t)s * DIM + col);
            float2 r;
            r.x = __uint_as_float(u << 16);
            r.y = __uint_as_float(u & 0xffff0000u);
            return r;
        } else {
            return *reinterpret_cast<const float2*>(h + (size_t)s * DIM + col);
        }
    };

    float a0x = 0.f, a0y = 0.f, a1x = 0.f, a1y = 0.f;
    float a2x = 0.f, a2y = 0.f, a3x = 0.f, a3y = 0.f;
    int e = start;
    for (; e + 8 <= end; e += 8) {
        int s0 = esrc[e],     s1 = esrc[e + 1], s2 = esrc[e + 2], s3 = esrc[e + 3];
        int s4 = esrc[e + 4], s5 = esrc[e + 5], s6 = esrc[e + 6], s7 = esrc[e + 7];
        float2 v0 = rowld(s0), v1 = rowld(s1), v2 = rowld(s2), v3 = rowld(s3);
        float2 v4 = rowld(s4), v5 = rowld(s5), v6 = rowld(s6), v7 = rowld(s7);
        a0x += v0.x; a0y += v0.y;  a1x += v1.x; a1y += v1.y;
        a2x += v2.x; a2y += v2.y;  a3x += v3.x; a3y += v3.y;
        a0x += v4.x; a0y += v4.y;  a1x += v5.x; a1y += v5.y;
        a2x += v6.x; a2y += v6.y;  a3x += v7.x; a3y += v7.y;
    }
    if (e + 4 <= end) {
        int s0 = esrc[e], s1 = esrc[e + 1], s2 = esrc[e + 2], s3 = esrc[e + 3];
        float2 v0 = rowld(s0), v1 = rowld(s1), v2 = rowld(s2), v3 = rowld(s3);
        a0x += v0.x; a0y += v0.y;  a1x += v1.x; a1y += v1.y;
        a2x += v2.x; a2y += v2.y;  a3x += v3.x; a3y += v3.y;
        e += 4;
    }
    if (e + 2 <= end) {
        int s0 = esrc[e], s1 = esrc[e + 1];
        float2 v0 = rowld(s0), v1 = rowld(s1);
        a0x += v0.x; a0y += v0.y;  a1x += v1.x; a1y += v1.y;
        e += 2;
    }
    if (e < end) {
        float2 v0 = rowld(esrc[e]);
        a0x += v0.x; a0y += v0.y;
    }
    float x0 = (a0x + a1x) + (a2x + a3x) - degf * hv.x;
    float x1 = (a0y + a1y) + (a2y + a3y) - degf * hv.y;

    float s = x0 * x0 + x1 * x1;
#pragma unroll
    for (int off = 32; off > 0; off >>= 1) s += __shfl_xor(s, off);
    float inv = 1.0f / (sqrtf(s) + 1e-7f);
    float2 o;
    o.x = x0 * inv;
    o.y = x1 * inv;
    *reinterpret_cast<float2*>(out + (size_t)v * DIM + col) = o;
}

extern "C" void kernel_launch(void* const* d_in, const int* in_sizes, int n_in,
                              void* d_out, int out_size, void* d_ws, size_t ws_size,
                              hipStream_t stream) {
    const float* h = (const float*)d_in[0];   // f32 [N,128]
    // d_in[1] = r, unused
    const int* src = (const int*)d_in[2];
    const int* dst = (const int*)d_in[3];
    float* out = (float*)d_out;

    const int N = in_sizes[0] / DIM;   // 50000
    const int E = in_sizes[2];         // 800000
    const int chunkSize = (E + NCHUNK - 1) / NCHUNK;   // 100000
    const int threads = 256;
    const int NB = (N + threads - 1) / threads;        // 196 (<=256)

    // Workspace: cnt8[8N] i32, cursor8[8N] i32, goff[N+1] i32, bsum[256],
    // boff[256], flag[1], esrc[E] u16, hb[N*DIM] bf16 (optional)
    int* cnt8    = (int*)d_ws;
    int* cursor8 = cnt8 + NCHUNK * N;
    int* goff    = cursor8 + NCHUNK * N;
    int* bsum    = goff + N + 1;
    int* boff    = bsum + 256;
    int* flag    = boff + 256;
    unsigned short* esrc = (unsigned short*)(flag + 1);
    unsigned short* hb   = esrc + E;   // E even -> 4B aligned

    size_t base_bytes = (size_t)((char*)hb - (char*)d_ws);
    bool use_bf16 = (ws_size >= base_bytes + (size_t)N * DIM * sizeof(unsigned short));

    hipMemsetAsync(cnt8, 0, (size_t)NCHUNK * N * sizeof(int), stream);
    hipMemsetAsync(flag, 0, sizeof(int), stream);

    detect_kernel<<<4, 256, 0, stream>>>(dst, flag);

    if (use_bf16) {
        int total4 = N * DIM / 4;
        cast_kernel<<<(total4 + threads - 1) / threads, threads, 0, stream>>>(h, hb, total4);
    }
    {
        int blocksPerChunk = (chunkSize + threads * 2 - 1) / (threads * 2);
        hist8_kernel<<<NCHUNK * blocksPerChunk, threads, 0, stream>>>(
            dst, cnt8, flag, E, chunkSize, N);
    }
    degsum_kernel<<<NB, threads, 0, stream>>>(cnt8, bsum, N);
    bscan_kernel<<<1, 256, 0, stream>>>(bsum, boff, goff, NB, N);
    offsets_kernel<<<NB, threads, 0, stream>>>(cnt8, boff, goff, cursor8, N);
    {
        int blocksPerChunk = (chunkSize + threads * 2 - 1) / (threads * 2);
        bucket8_kernel<<<NCHUNK * blocksPerChunk, threads, 0, stream>>>(
            src, dst, cursor8, esrc, flag, E, chunkSize, N);
    }
    {
        int blocks = (N + 3) / 4;   // 4 waves per block
        if (use_bf16)
            gather_kernel<true><<<blocks, threads, 0, stream>>>(h, hb, goff, esrc, out, N);
        else
            gather_kernel<false><<<blocks, threads, 0, stream>>>(h, hb, goff, esrc, out, N);
    }
}